// Round 10
// baseline (176.754 us; speedup 1.0000x reference)
//
#include <hip/hip_runtime.h>
#include <hip/hip_bf16.h>
#include <hip/hip_fp16.h>
#include <math.h>

#define HIDDEN 1024
#define NCLS 64
#define NB2 784         // fine groups: group = dst >> 6
#define BCAP2 2560      // per-group capacity (mean 2046)
#define CHUNK 4096      // edges per bucket block
#define KSTEP 32
#define NKS 32          // 1024 / KSTEP
#define BUF 16384       // A 8KB | Bh 4KB | Bl 4KB
#define RING 4

typedef __attribute__((ext_vector_type(8))) short short8;
typedef __attribute__((ext_vector_type(4))) float f32x4;
typedef __attribute__((ext_vector_type(8))) _Float16 half8;

__device__ __forceinline__ short f2bf(float f) {
    __hip_bfloat16 b = __float2bfloat16(f);
    return __builtin_bit_cast(short, b);
}
__device__ __forceinline__ float bf2f(short s) {
    unsigned u = ((unsigned)(unsigned short)s) << 16;
    return __builtin_bit_cast(float, u);
}

__device__ __forceinline__ void async_copy16(void* lds, const void* g) {
    __builtin_amdgcn_global_load_lds(
        (const __attribute__((address_space(1))) unsigned int*)g,
        (__attribute__((address_space(3))) unsigned int*)lds, 16, 0, 0);
}

// ---------------- W prep: transpose + split bf16 hi/lo, layout [c][k] ----------------
__global__ void wprep_kernel(const float* __restrict__ W,
                             short* __restrict__ wt_hi, short* __restrict__ wt_lo) {
    int idx = blockIdx.x * 256 + threadIdx.x;
    int c = idx >> 10;
    int k = idx & 1023;
    float f = W[(size_t)k * NCLS + c];
    short hb = f2bf(f);
    wt_hi[idx] = hb;
    wt_lo[idx] = f2bf(f - bf2f(hb));
}

// ================= bucket: per-chunk scatter into fine dst-groups =================
__global__ __launch_bounds__(256) void bucket_kernel(const int* __restrict__ ei,
                                                     unsigned* __restrict__ pairs2,
                                                     int* __restrict__ bcnt2, int E) {
    __shared__ __align__(16) char smem[32800];
    int* hist  = (int*)smem;
    int* offs  = hist + 1024;
    int* cur   = offs + 1024;
    int* gbase = cur + 1024;
    unsigned* stage = (unsigned*)(gbase + 1024);
    int* nz = (int*)(stage + CHUNK);
    int* wsum = nz + 1;

    const int tid = threadIdx.x;
    const int base = blockIdx.x * CHUNK;
    const int cnt_c = min(CHUNK, E - base);

    if (tid == 0) *nz = 0;
    #pragma unroll
    for (int j = 0; j < 4; ++j) { hist[tid + 256 * j] = 0; cur[tid + 256 * j] = 0; }
    __syncthreads();

    int found = 0;
    for (int j = tid; j < 1024; j += 256) {
        int e = base + j;
        if (e < E) found |= (ei[2 * e + 1] != 0);
    }
    if (found) atomicOr(nz, 1);
    __syncthreads();
    const int is64 = (*nz == 0);

    unsigned pr[16];
    #pragma unroll
    for (int j = 0; j < 16; ++j) {
        int e = base + j * 256 + tid;
        unsigned p = 0xFFFFFFFFu;
        if (e < E) {
            int s = is64 ? ei[2 * e] : ei[e];
            int d = is64 ? ei[2 * (E + e)] : ei[E + e];
            p = (unsigned)s | ((unsigned)d << 16);
            atomicAdd(&hist[d >> 6], 1);
        }
        pr[j] = p;
    }
    __syncthreads();

    const int b0 = 4 * tid;
    int h0 = hist[b0], h1 = hist[b0 + 1], h2 = hist[b0 + 2], h3 = hist[b0 + 3];
    int S = h0 + h1 + h2 + h3;
    int incl = S;
    #pragma unroll
    for (int d = 1; d < 64; d <<= 1) {
        int t2 = __shfl_up(incl, d);
        if ((tid & 63) >= d) incl += t2;
    }
    if ((tid & 63) == 63) wsum[tid >> 6] = incl;
    __syncthreads();
    int pre = 0;
    #pragma unroll
    for (int w = 0; w < 4; ++w)
        if (w < (tid >> 6)) pre += wsum[w];
    int ex = pre + incl - S;
    offs[b0] = ex;
    offs[b0 + 1] = ex + h0;
    offs[b0 + 2] = ex + h0 + h1;
    offs[b0 + 3] = ex + h0 + h1 + h2;
    if (h0 > 0) gbase[b0] = atomicAdd(&bcnt2[b0], h0);
    if (h1 > 0) gbase[b0 + 1] = atomicAdd(&bcnt2[b0 + 1], h1);
    if (h2 > 0) gbase[b0 + 2] = atomicAdd(&bcnt2[b0 + 2], h2);
    if (h3 > 0) gbase[b0 + 3] = atomicAdd(&bcnt2[b0 + 3], h3);
    __syncthreads();

    #pragma unroll
    for (int j = 0; j < 16; ++j) {
        unsigned p = pr[j];
        if (p != 0xFFFFFFFFu) {
            int b = (int)(p >> 22);
            int pos = offs[b] + atomicAdd(&cur[b], 1);
            stage[pos] = p;
        }
    }
    __syncthreads();
    for (int i = tid; i < cnt_c; i += 256) {
        unsigned p = stage[i];
        int b = (int)(p >> 22);
        pairs2[(size_t)b * BCAP2 + gbase[b] + (i - offs[b])] = p;
    }
}

// ======== GEMM: h16 = fp16(x @ W), 4-deep ring pipeline, K-step 32 ========
// LDS buffer (16KB): A[64 rows][32 floats] row-major 128B/row, 16B-chunk XOR-swz
//   (chunk j of row r holds global chunk j^(r&7));
// Bh/Bl[64 cols][32 shorts] col-major 64B/col (chunk j of col c = global j^(c&3)).
__global__ __launch_bounds__(256) void gemm_kernel(const float* __restrict__ x,
                                                   const short* __restrict__ wt_hi,
                                                   const short* __restrict__ wt_lo,
                                                   _Float16* __restrict__ h16, int M,
                                                   int nTiles, int* __restrict__ tile_ctr) {
    __shared__ __align__(16) char smem[RING * BUF];
    __shared__ int s_tile;
    const int tid = threadIdx.x;
    const int wave = tid >> 6;
    const int lane = tid & 63;
    const int l15 = lane & 15, l4 = lane >> 4;

    // staging source geometry (row0-relative)
    const int ar0 = wave * 16 + (lane >> 3);        // A load 0: local row
    const int ar1 = wave * 16 + 8 + (lane >> 3);    // A load 1
    const int ag  = ((lane & 7) ^ ((lane >> 3) & 7)) * 4;   // pre-swz float offset
    const int bcol = wave * 16 + (lane >> 2);
    const int bg  = ((lane & 3) ^ ((lane >> 2) & 3)) * 8;   // pre-swz short offset

    const int rt = wave * 16 + l15;  // this lane's A row for MFMA

    for (;;) {
        __syncthreads();
        if (tid == 0) s_tile = atomicAdd(tile_ctr, 1);
        __syncthreads();
        const int t = s_tile;
        if (t >= nTiles) break;
        const int row0 = t * 64;

        const float* ap0 = x + (size_t)min(row0 + ar0, M - 1) * HIDDEN + ag;
        const float* ap1 = x + (size_t)min(row0 + ar1, M - 1) * HIDDEN + ag;
        const short* bhp = wt_hi + (size_t)bcol * HIDDEN + bg;
        const short* blp = wt_lo + (size_t)bcol * HIDDEN + bg;

        auto stage = [&](int step) {
            int k0 = min(step, NKS - 1) * KSTEP;  // clamped tail: re-reads hot lines
            char* buf = smem + (step & (RING - 1)) * BUF;
            async_copy16(buf + wave * 2048, ap0 + k0);
            async_copy16(buf + wave * 2048 + 1024, ap1 + k0);
            async_copy16(buf + 8192 + wave * 1024, bhp + k0);
            async_copy16(buf + 12288 + wave * 1024, blp + k0);
        };

        f32x4 acc[4];
        #pragma unroll
        for (int nf = 0; nf < 4; ++nf) acc[nf] = (f32x4){0.f, 0.f, 0.f, 0.f};

        stage(0); stage(1); stage(2);
        for (int tt = 0; tt < NKS; ++tt) {
            stage(tt + 3);  // uniform: 16 outstanding after this
            asm volatile("s_waitcnt vmcnt(12)\n\ts_barrier" ::: "memory");
            char* buf = smem + (tt & (RING - 1)) * BUF;
            const int abyte = rt * 128;
            f32x4 af0 = *reinterpret_cast<const f32x4*>(
                buf + abyte + (((l4 * 2) ^ (rt & 7)) * 16));
            f32x4 af1 = *reinterpret_cast<const f32x4*>(
                buf + abyte + (((l4 * 2 + 1) ^ (rt & 7)) * 16));
            short8 ah, al;
            #pragma unroll
            for (int j = 0; j < 4; ++j) {
                short hb = f2bf(af0[j]);
                ah[j] = hb;
                al[j] = f2bf(af0[j] - bf2f(hb));
                short hb2 = f2bf(af1[j]);
                ah[j + 4] = hb2;
                al[j + 4] = f2bf(af1[j] - bf2f(hb2));
            }
            #pragma unroll
            for (int nf = 0; nf < 4; ++nf) {
                int c = l15 + 16 * nf;
                int bo = 8192 + c * 64 + ((l4 ^ (c & 3)) * 16);
                short8 bh = *reinterpret_cast<const short8*>(buf + bo);
                short8 bl = *reinterpret_cast<const short8*>(buf + bo + 4096);
                acc[nf] = __builtin_amdgcn_mfma_f32_16x16x32_bf16(ah, bh, acc[nf], 0, 0, 0);
                acc[nf] = __builtin_amdgcn_mfma_f32_16x16x32_bf16(al, bh, acc[nf], 0, 0, 0);
                acc[nf] = __builtin_amdgcn_mfma_f32_16x16x32_bf16(ah, bl, acc[nf], 0, 0, 0);
            }
            asm volatile("s_barrier" ::: "memory");
        }
        asm volatile("s_waitcnt vmcnt(0)" ::: "memory");  // drain clamped tail stages

        #pragma unroll
        for (int j = 0; j < 4; ++j) {
            int r = row0 + wave * 16 + l4 * 4 + j;
            if (r < M) {
                #pragma unroll
                for (int nf = 0; nf < 4; ++nf) {
                    h16[(size_t)r * NCLS + l15 + 16 * nf] = (_Float16)acc[nf][j];
                }
            }
        }
    }
}

// ---------------- per-group degree -> dis ----------------
__global__ __launch_bounds__(256) void degree_kernel(const unsigned* __restrict__ pairs2,
                                                     const int* __restrict__ bcnt2,
                                                     float* __restrict__ dis, int n) {
    __shared__ int hist[256];
    const int tid = threadIdx.x;
    hist[tid] = 0;
    __syncthreads();
    #pragma unroll
    for (int gg = 0; gg < 4; ++gg) {
        int g = blockIdx.x * 4 + gg;
        const int cb = bcnt2[g];
        const unsigned* bp = pairs2 + (size_t)g * BCAP2;
        for (int i = tid; i < cb; i += 256)
            atomicAdd(&hist[gg * 64 + ((bp[i] >> 16) & 63)], 1);
    }
    __syncthreads();
    int node = blockIdx.x * 256 + tid;
    if (node < n) dis[node] = rsqrtf((float)hist[tid] + 1.0f);
}

// ---------------- agg v5: one block per 64-node group ----------------
__global__ __launch_bounds__(256) void agg_kernel(const unsigned* __restrict__ pairs2,
                                                  const int* __restrict__ bcnt2,
                                                  const _Float16* __restrict__ h16,
                                                  const float* __restrict__ dis,
                                                  const float* __restrict__ bias,
                                                  float* __restrict__ out, int n) {
    __shared__ int hist[64];
    __shared__ int offs[64];
    __shared__ int cur[64];
    __shared__ unsigned short ssrc[BCAP2];
    __shared__ float swt[BCAP2];
    const int tid = threadIdx.x;
    const int grp = blockIdx.x;
    const int base_node = grp * 64;
    if (base_node >= n) return;
    if (tid < 64) { hist[tid] = 0; cur[tid] = 0; }
    __syncthreads();
    const int cb = bcnt2[grp];
    const unsigned* bp = pairs2 + (size_t)grp * BCAP2;
    for (int i = tid; i < cb; i += 256)
        atomicAdd(&hist[(bp[i] >> 16) & 63], 1);
    __syncthreads();
    if (tid == 0) {
        int r = 0;
        #pragma unroll
        for (int k = 0; k < 64; ++k) { offs[k] = r; r += hist[k]; }
    }
    __syncthreads();
    for (int i = tid; i < cb; i += 256) {
        unsigned p = bp[i];
        int ln = (p >> 16) & 63;
        int pos = offs[ln] + atomicAdd(&cur[ln], 1);
        int s = (int)(p & 0xFFFFu);
        ssrc[pos] = (unsigned short)s;
        swt[pos] = dis[s];
    }
    __syncthreads();

    const int wave = tid >> 6;
    const int lane = tid & 63;
    const int q = lane & 7;
    const int g = lane >> 3;
    float bv[8];
    #pragma unroll
    for (int c = 0; c < 8; ++c) bv[c] = bias[q * 8 + c];

    for (int t = 0; t < 16; ++t) {
        int ln = wave * 16 + t;
        int node = base_node + ln;
        if (node >= n) continue;
        int len = hist[ln];
        int e0 = offs[ln];
        float di = rsqrtf((float)len + 1.0f);

        half8 hs = *reinterpret_cast<const half8*>(h16 + (size_t)node * NCLS + q * 8);
        float selfw = (g == 0) ? di : 0.f;
        float a[8], a2[8];
        #pragma unroll
        for (int c = 0; c < 8; ++c) { a[c] = (float)hs[c] * selfw; a2[c] = 0.f; }

        for (int i = 0; i < len; i += 16) {
            int i1 = i + g;
            bool v1 = i1 < len;
            int s1 = v1 ? (int)ssrc[e0 + i1] : 0;
            float w1 = v1 ? swt[e0 + i1] : 0.f;
            half8 r1 = *reinterpret_cast<const half8*>(h16 + (size_t)s1 * NCLS + q * 8);
            if (i + 8 < len) {
                int i2 = i + 8 + g;
                bool v2 = i2 < len;
                int s2 = v2 ? (int)ssrc[e0 + i2] : 0;
                float w2 = v2 ? swt[e0 + i2] : 0.f;
                half8 r2 = *reinterpret_cast<const half8*>(h16 + (size_t)s2 * NCLS + q * 8);
                #pragma unroll
                for (int c = 0; c < 8; ++c) a2[c] += w2 * (float)r2[c];
            }
            #pragma unroll
            for (int c = 0; c < 8; ++c) a[c] += w1 * (float)r1[c];
        }
        #pragma unroll
        for (int c = 0; c < 8; ++c) {
            float s = a[c] + a2[c];
            s += __shfl_xor(s, 8);
            s += __shfl_xor(s, 16);
            s += __shfl_xor(s, 32);
            a[c] = s * di + bv[c];
        }
        float m = a[0];
        #pragma unroll
        for (int c = 1; c < 8; ++c) m = fmaxf(m, a[c]);
        #pragma unroll
        for (int d = 1; d < 8; d <<= 1) m = fmaxf(m, __shfl_xor(m, d));
        float ex[8], sum = 0.f;
        #pragma unroll
        for (int c = 0; c < 8; ++c) { ex[c] = __expf(a[c] - m); sum += ex[c]; }
        #pragma unroll
        for (int d = 1; d < 8; d <<= 1) sum += __shfl_xor(sum, d);
        float inv = 1.f / sum;
        if (g == 0) {
            f32x4 o0 = {ex[0] * inv, ex[1] * inv, ex[2] * inv, ex[3] * inv};
            f32x4 o1 = {ex[4] * inv, ex[5] * inv, ex[6] * inv, ex[7] * inv};
            *reinterpret_cast<f32x4*>(out + (size_t)node * NCLS + q * 8) = o0;
            *reinterpret_cast<f32x4*>(out + (size_t)node * NCLS + q * 8 + 4) = o1;
        }
    }
}

// ---------------- launcher ----------------
extern "C" void kernel_launch(void* const* d_in, const int* in_sizes, int n_in,
                              void* d_out, int out_size, void* d_ws, size_t ws_size,
                              hipStream_t stream) {
    const float* x    = (const float*)d_in[0];
    const int*   ei   = (const int*)d_in[1];
    const float* W    = (const float*)d_in[2];
    const float* bias = (const float*)d_in[3];
    float* out = (float*)d_out;

    const int n = in_sizes[0] / HIDDEN;   // 50000
    const int E = in_sizes[1] / 2;        // 1600000

    char* ws = (char*)d_ws;
    size_t off = 0;
    auto alloc = [&](size_t bytes) -> void* {
        void* p = (void*)(ws + off);
        off = (off + bytes + 255) & ~((size_t)255);
        return p;
    };
    int*      bcnt2  = (int*)alloc((size_t)(NB2 + 1) * 4);  // counts + tile queue
    unsigned* pairs2 = (unsigned*)alloc((size_t)NB2 * BCAP2 * 4);
    float*    dis    = (float*)alloc((size_t)n * 4);
    _Float16* h16    = (_Float16*)alloc((size_t)n * NCLS * 2);
    short*    wt_hi  = (short*)alloc((size_t)NCLS * HIDDEN * 2);
    short*    wt_lo  = (short*)alloc((size_t)NCLS * HIDDEN * 2);
    (void)ws_size;

    hipMemsetAsync(bcnt2, 0, (size_t)(NB2 + 1) * 4, stream);

    wprep_kernel<<<(NCLS * HIDDEN) / 256, 256, 0, stream>>>(W, wt_hi, wt_lo);

    const int nBucketBlocks = (E + CHUNK - 1) / CHUNK; // 391
    bucket_kernel<<<nBucketBlocks, 256, 0, stream>>>(ei, pairs2, bcnt2, E);

    const int nTiles = (n + 63) / 64;                  // 782
    gemm_kernel<<<512, 256, 0, stream>>>(x, wt_hi, wt_lo, h16, n, nTiles, bcnt2 + NB2);

    const int nGroups = (n + 63) / 64;                 // 782
    degree_kernel<<<(nGroups + 3) / 4, 256, 0, stream>>>(pairs2, bcnt2, dis, n);
    agg_kernel<<<nGroups, 256, 0, stream>>>(pairs2, bcnt2, h16, dis, bias, out, n);
}

// Round 11
// 139.594 us; speedup vs baseline: 1.2662x; 1.2662x over previous
//
#include <hip/hip_runtime.h>
#include <hip/hip_bf16.h>
#include <hip/hip_fp16.h>
#include <math.h>

#define HIDDEN 1024
#define NCLS 64
#define NB2 784         // fine groups: group = dst >> 6
#define BCAP2 2560      // per-group capacity (mean 2046)
#define CHUNK 4096      // edges per bucket block
#define SMEM_BYTES 49920  // gemm: A 32*1040 + Bh 8*1040 + Bl 8*1040; bucket needs 32788

typedef __attribute__((ext_vector_type(8))) short short8;
typedef __attribute__((ext_vector_type(4))) float f32x4;
typedef __attribute__((ext_vector_type(8))) _Float16 half8;

__device__ __forceinline__ short f2bf(float f) {
    __hip_bfloat16 b = __float2bfloat16(f);
    return __builtin_bit_cast(short, b);
}
__device__ __forceinline__ float bf2f(short s) {
    unsigned u = ((unsigned)(unsigned short)s) << 16;
    return __builtin_bit_cast(float, u);
}

__device__ __forceinline__ void async_copy16(void* lds, const void* g) {
    __builtin_amdgcn_global_load_lds(
        (const __attribute__((address_space(1))) unsigned int*)g,
        (__attribute__((address_space(3))) unsigned int*)lds, 16, 0, 0);
}

// ---------------- W prep: transpose + split bf16 hi/lo, layout [c][k] ----------------
__global__ void wprep_kernel(const float* __restrict__ W,
                             short* __restrict__ wt_hi, short* __restrict__ wt_lo) {
    int idx = blockIdx.x * 256 + threadIdx.x;
    int c = idx >> 10;
    int k = idx & 1023;
    float f = W[(size_t)k * NCLS + c];
    short hb = f2bf(f);
    wt_hi[idx] = hb;
    wt_lo[idx] = f2bf(f - bf2f(hb));
}

// ================= bucket role: per-chunk scatter into fine dst-groups =================
__device__ void bucket_body(char* smem, const int* __restrict__ ei,
                            unsigned* __restrict__ pairs2, int* __restrict__ bcnt2,
                            int E, int bid) {
    int* hist  = (int*)smem;
    int* offs  = hist + 1024;
    int* cur   = offs + 1024;
    int* gbase = cur + 1024;
    unsigned* stage = (unsigned*)(gbase + 1024);
    int* nz = (int*)(stage + CHUNK);
    int* wsum = nz + 1;

    const int tid = threadIdx.x;
    const int base = bid * CHUNK;
    const int cnt_c = min(CHUNK, E - base);

    if (tid == 0) *nz = 0;
    #pragma unroll
    for (int j = 0; j < 4; ++j) { hist[tid + 256 * j] = 0; cur[tid + 256 * j] = 0; }
    __syncthreads();

    int found = 0;
    for (int j = tid; j < 1024; j += 256) {
        int e = base + j;
        if (e < E) found |= (ei[2 * e + 1] != 0);
    }
    if (found) atomicOr(nz, 1);
    __syncthreads();
    const int is64 = (*nz == 0);

    unsigned pr[16];
    #pragma unroll
    for (int j = 0; j < 16; ++j) {
        int e = base + j * 256 + tid;
        unsigned p = 0xFFFFFFFFu;
        if (e < E) {
            int s = is64 ? ei[2 * e] : ei[e];
            int d = is64 ? ei[2 * (E + e)] : ei[E + e];
            p = (unsigned)s | ((unsigned)d << 16);
            atomicAdd(&hist[d >> 6], 1);
        }
        pr[j] = p;
    }
    __syncthreads();

    const int b0 = 4 * tid;
    int h0 = hist[b0], h1 = hist[b0 + 1], h2 = hist[b0 + 2], h3 = hist[b0 + 3];
    int S = h0 + h1 + h2 + h3;
    int incl = S;
    #pragma unroll
    for (int d = 1; d < 64; d <<= 1) {
        int t2 = __shfl_up(incl, d);
        if ((tid & 63) >= d) incl += t2;
    }
    if ((tid & 63) == 63) wsum[tid >> 6] = incl;
    __syncthreads();
    int pre = 0;
    #pragma unroll
    for (int w = 0; w < 4; ++w)
        if (w < (tid >> 6)) pre += wsum[w];
    int ex = pre + incl - S;
    offs[b0] = ex;
    offs[b0 + 1] = ex + h0;
    offs[b0 + 2] = ex + h0 + h1;
    offs[b0 + 3] = ex + h0 + h1 + h2;
    if (h0 > 0) gbase[b0] = atomicAdd(&bcnt2[b0], h0);
    if (h1 > 0) gbase[b0 + 1] = atomicAdd(&bcnt2[b0 + 1], h1);
    if (h2 > 0) gbase[b0 + 2] = atomicAdd(&bcnt2[b0 + 2], h2);
    if (h3 > 0) gbase[b0 + 3] = atomicAdd(&bcnt2[b0 + 3], h3);
    __syncthreads();

    #pragma unroll
    for (int j = 0; j < 16; ++j) {
        unsigned p = pr[j];
        if (p != 0xFFFFFFFFu) {
            int b = (int)(p >> 22);
            int pos = offs[b] + atomicAdd(&cur[b], 1);
            stage[pos] = p;
        }
    }
    __syncthreads();
    for (int i = tid; i < cnt_c; i += 256) {
        unsigned p = stage[i];
        int b = (int)(p >> 22);
        pairs2[(size_t)b * BCAP2 + gbase[b] + (i - offs[b])] = p;
    }
}

// ====== GEMM role: 128x64 tile, 32 rows/wave, single-buffer, split-bf16 MFMA ======
// LDS: A = 32 chunks x 1040B (chunk q holds rows 4q..4q+3, 256B/row, 16B-slot j
// holds global chunk j^((row&3)<<2)); Bh/Bl = 8 chunks x 1040B (chunk q cols
// 8q..8q+7, 128B/col, slot j holds global chunk j^(col&7)).
__device__ void gemm_body(char* smem, const float* __restrict__ x,
                          const short* __restrict__ wt_hi, const short* __restrict__ wt_lo,
                          _Float16* __restrict__ h16, int M, int bid) {
    char* As = smem;
    char* Bh = smem + 32 * 1040;
    char* Bl = smem + 40 * 1040;

    const int tid = threadIdx.x;
    const int wave = tid >> 6;
    const int lane = tid & 63;
    const int l15 = lane & 15, l4 = lane >> 4;
    const int row0 = bid * 128;

    // staging sources: 8 A-chunks per wave, 2 Bh + 2 Bl per wave
    const float* agp[8];
    #pragma unroll
    for (int i = 0; i < 8; ++i) {
        int rg = row0 + (wave * 8 + i) * 4 + (lane >> 4);
        if (rg > M - 1) rg = M - 1;
        int g = (lane & 15) ^ (((lane >> 4) & 3) << 2);
        agp[i] = x + (size_t)rg * HIDDEN + g * 4;
    }
    const short* bhp[2];
    const short* blp[2];
    #pragma unroll
    for (int i = 0; i < 2; ++i) {
        int c = (wave * 2 + i) * 8 + (lane >> 3);
        int g = (lane & 7) ^ ((lane >> 3) & 7);
        bhp[i] = wt_hi + (size_t)c * HIDDEN + g * 8;
        blp[i] = wt_lo + (size_t)c * HIDDEN + g * 8;
    }

    f32x4 accP[2][4], accQ[2][4];
    #pragma unroll
    for (int f = 0; f < 2; ++f)
        #pragma unroll
        for (int nf = 0; nf < 4; ++nf) {
            accP[f][nf] = (f32x4){0.f, 0.f, 0.f, 0.f};
            accQ[f][nf] = (f32x4){0.f, 0.f, 0.f, 0.f};
        }

    const int rt = wave * 32 + l15;   // frag0 row; frag1 = rt+16 (same &3)
    const int r3 = rt & 3;
    char* arow0 = As + (rt >> 2) * 1040 + r3 * 256;
    char* arow1 = arow0 + 4 * 1040;   // +16 rows = +4 chunks

    for (int k0 = 0; k0 < HIDDEN; k0 += 64) {
        #pragma unroll
        for (int i = 0; i < 8; ++i)
            async_copy16(As + (wave * 8 + i) * 1040, agp[i] + k0);
        #pragma unroll
        for (int i = 0; i < 2; ++i) {
            async_copy16(Bh + (wave * 2 + i) * 1040, bhp[i] + k0);
            async_copy16(Bl + (wave * 2 + i) * 1040, blp[i] + k0);
        }
        __syncthreads();

        #pragma unroll
        for (int kk = 0; kk < 2; ++kk) {
            int js = (kk * 8 + l4 * 2) ^ (r3 << 2);
            f32x4 a00 = *reinterpret_cast<const f32x4*>(arow0 + js * 16);
            f32x4 a01 = *reinterpret_cast<const f32x4*>(arow0 + (js ^ 1) * 16);
            f32x4 a10 = *reinterpret_cast<const f32x4*>(arow1 + js * 16);
            f32x4 a11 = *reinterpret_cast<const f32x4*>(arow1 + (js ^ 1) * 16);
            // js and js^1 are the two consecutive 16B slots (kk*8+l4*2, +1) swizzled;
            // note (kk*8+l4*2)^(r3<<2) with +1: since l4*2 is even, slot+1 = js^1.
            short8 ah0, al0, ah1, al1;
            #pragma unroll
            for (int j = 0; j < 4; ++j) {
                short hb;
                hb = f2bf(a00[j]); ah0[j] = hb; al0[j] = f2bf(a00[j] - bf2f(hb));
                hb = f2bf(a01[j]); ah0[j + 4] = hb; al0[j + 4] = f2bf(a01[j] - bf2f(hb));
                hb = f2bf(a10[j]); ah1[j] = hb; al1[j] = f2bf(a10[j] - bf2f(hb));
                hb = f2bf(a11[j]); ah1[j + 4] = hb; al1[j + 4] = f2bf(a11[j] - bf2f(hb));
            }
            #pragma unroll
            for (int nf = 0; nf < 4; ++nf) {
                int c = l15 + 16 * nf;
                int jb = (kk * 4 + l4) ^ (c & 7);
                size_t boff = (size_t)(c >> 3) * 1040 + (c & 7) * 128 + jb * 16;
                short8 bh = *reinterpret_cast<const short8*>(Bh + boff);
                short8 bl = *reinterpret_cast<const short8*>(Bl + boff);
                accP[0][nf] = __builtin_amdgcn_mfma_f32_16x16x32_bf16(ah0, bh, accP[0][nf], 0, 0, 0);
                accP[0][nf] = __builtin_amdgcn_mfma_f32_16x16x32_bf16(al0, bh, accP[0][nf], 0, 0, 0);
                accQ[0][nf] = __builtin_amdgcn_mfma_f32_16x16x32_bf16(ah0, bl, accQ[0][nf], 0, 0, 0);
                accP[1][nf] = __builtin_amdgcn_mfma_f32_16x16x32_bf16(ah1, bh, accP[1][nf], 0, 0, 0);
                accP[1][nf] = __builtin_amdgcn_mfma_f32_16x16x32_bf16(al1, bh, accP[1][nf], 0, 0, 0);
                accQ[1][nf] = __builtin_amdgcn_mfma_f32_16x16x32_bf16(ah1, bl, accQ[1][nf], 0, 0, 0);
            }
        }
        __syncthreads();
    }

    #pragma unroll
    for (int f = 0; f < 2; ++f) {
        #pragma unroll
        for (int j = 0; j < 4; ++j) {
            int r = row0 + wave * 32 + f * 16 + l4 * 4 + j;
            if (r < M) {
                #pragma unroll
                for (int nf = 0; nf < 4; ++nf) {
                    h16[(size_t)r * NCLS + l15 + 16 * nf] =
                        (_Float16)(accP[f][nf][j] + accQ[f][nf][j]);
                }
            }
        }
    }
}

// ===== fat: gemm blocks (XCD-swizzled tiles) first, bucket blocks after =====
__global__ __launch_bounds__(256) void fat_kernel(const float* __restrict__ x,
                                                  const short* __restrict__ wt_hi,
                                                  const short* __restrict__ wt_lo,
                                                  _Float16* __restrict__ h16, int M,
                                                  const int* __restrict__ ei,
                                                  unsigned* __restrict__ pairs2,
                                                  int* __restrict__ bcnt2, int E,
                                                  int nGemm) {
    __shared__ __align__(16) char smem[SMEM_BYTES];
    const int bid = blockIdx.x;
    if (bid < nGemm) {
        // bijective XCD-chunk swizzle (m204): each XCD gets a contiguous tile range
        const int q = nGemm >> 3, r = nGemm & 7;
        int xcd = bid & 7, i = bid >> 3;
        int t = (xcd < r ? xcd * (q + 1) : r * (q + 1) + (xcd - r) * q) + i;
        gemm_body(smem, x, wt_hi, wt_lo, h16, M, t);
    } else {
        bucket_body(smem, ei, pairs2, bcnt2, E, bid - nGemm);
    }
}

// ---------------- per-group degree -> dis ----------------
__global__ __launch_bounds__(256) void degree_kernel(const unsigned* __restrict__ pairs2,
                                                     const int* __restrict__ bcnt2,
                                                     float* __restrict__ dis, int n) {
    __shared__ int hist[256];
    const int tid = threadIdx.x;
    hist[tid] = 0;
    __syncthreads();
    #pragma unroll
    for (int gg = 0; gg < 4; ++gg) {
        int g = blockIdx.x * 4 + gg;
        const int cb = bcnt2[g];
        const unsigned* bp = pairs2 + (size_t)g * BCAP2;
        for (int i = tid; i < cb; i += 256)
            atomicAdd(&hist[gg * 64 + ((bp[i] >> 16) & 63)], 1);
    }
    __syncthreads();
    int node = blockIdx.x * 256 + tid;
    if (node < n) dis[node] = rsqrtf((float)hist[tid] + 1.0f);
}

// ---------------- agg v5: one block per 64-node group ----------------
__global__ __launch_bounds__(256) void agg_kernel(const unsigned* __restrict__ pairs2,
                                                  const int* __restrict__ bcnt2,
                                                  const _Float16* __restrict__ h16,
                                                  const float* __restrict__ dis,
                                                  const float* __restrict__ bias,
                                                  float* __restrict__ out, int n) {
    __shared__ int hist[64];
    __shared__ int offs[64];
    __shared__ int cur[64];
    __shared__ unsigned short ssrc[BCAP2];
    __shared__ float swt[BCAP2];
    const int tid = threadIdx.x;
    const int grp = blockIdx.x;
    const int base_node = grp * 64;
    if (base_node >= n) return;
    if (tid < 64) { hist[tid] = 0; cur[tid] = 0; }
    __syncthreads();
    const int cb = bcnt2[grp];
    const unsigned* bp = pairs2 + (size_t)grp * BCAP2;
    for (int i = tid; i < cb; i += 256)
        atomicAdd(&hist[(bp[i] >> 16) & 63], 1);
    __syncthreads();
    if (tid == 0) {
        int r = 0;
        #pragma unroll
        for (int k = 0; k < 64; ++k) { offs[k] = r; r += hist[k]; }
    }
    __syncthreads();
    for (int i = tid; i < cb; i += 256) {
        unsigned p = bp[i];
        int ln = (p >> 16) & 63;
        int pos = offs[ln] + atomicAdd(&cur[ln], 1);
        int s = (int)(p & 0xFFFFu);
        ssrc[pos] = (unsigned short)s;
        swt[pos] = dis[s];
    }
    __syncthreads();

    const int wave = tid >> 6;
    const int lane = tid & 63;
    const int q = lane & 7;
    const int g = lane >> 3;
    float bv[8];
    #pragma unroll
    for (int c = 0; c < 8; ++c) bv[c] = bias[q * 8 + c];

    for (int t = 0; t < 16; ++t) {
        int ln = wave * 16 + t;
        int node = base_node + ln;
        if (node >= n) continue;
        int len = hist[ln];
        int e0 = offs[ln];
        float di = rsqrtf((float)len + 1.0f);

        half8 hs = *reinterpret_cast<const half8*>(h16 + (size_t)node * NCLS + q * 8);
        float selfw = (g == 0) ? di : 0.f;
        float a[8], a2[8];
        #pragma unroll
        for (int c = 0; c < 8; ++c) { a[c] = (float)hs[c] * selfw; a2[c] = 0.f; }

        for (int i = 0; i < len; i += 16) {
            int i1 = i + g;
            bool v1 = i1 < len;
            int s1 = v1 ? (int)ssrc[e0 + i1] : 0;
            float w1 = v1 ? swt[e0 + i1] : 0.f;
            half8 r1 = *reinterpret_cast<const half8*>(h16 + (size_t)s1 * NCLS + q * 8);
            if (i + 8 < len) {
                int i2 = i + 8 + g;
                bool v2 = i2 < len;
                int s2 = v2 ? (int)ssrc[e0 + i2] : 0;
                float w2 = v2 ? swt[e0 + i2] : 0.f;
                half8 r2 = *reinterpret_cast<const half8*>(h16 + (size_t)s2 * NCLS + q * 8);
                #pragma unroll
                for (int c = 0; c < 8; ++c) a2[c] += w2 * (float)r2[c];
            }
            #pragma unroll
            for (int c = 0; c < 8; ++c) a[c] += w1 * (float)r1[c];
        }
        #pragma unroll
        for (int c = 0; c < 8; ++c) {
            float s = a[c] + a2[c];
            s += __shfl_xor(s, 8);
            s += __shfl_xor(s, 16);
            s += __shfl_xor(s, 32);
            a[c] = s * di + bv[c];
        }
        float m = a[0];
        #pragma unroll
        for (int c = 1; c < 8; ++c) m = fmaxf(m, a[c]);
        #pragma unroll
        for (int d = 1; d < 8; d <<= 1) m = fmaxf(m, __shfl_xor(m, d));
        float ex[8], sum = 0.f;
        #pragma unroll
        for (int c = 0; c < 8; ++c) { ex[c] = __expf(a[c] - m); sum += ex[c]; }
        #pragma unroll
        for (int d = 1; d < 8; d <<= 1) sum += __shfl_xor(sum, d);
        float inv = 1.f / sum;
        if (g == 0) {
            f32x4 o0 = {ex[0] * inv, ex[1] * inv, ex[2] * inv, ex[3] * inv};
            f32x4 o1 = {ex[4] * inv, ex[5] * inv, ex[6] * inv, ex[7] * inv};
            *reinterpret_cast<f32x4*>(out + (size_t)node * NCLS + q * 8) = o0;
            *reinterpret_cast<f32x4*>(out + (size_t)node * NCLS + q * 8 + 4) = o1;
        }
    }
}

// ---------------- launcher ----------------
extern "C" void kernel_launch(void* const* d_in, const int* in_sizes, int n_in,
                              void* d_out, int out_size, void* d_ws, size_t ws_size,
                              hipStream_t stream) {
    const float* x    = (const float*)d_in[0];
    const int*   ei   = (const int*)d_in[1];
    const float* W    = (const float*)d_in[2];
    const float* bias = (const float*)d_in[3];
    float* out = (float*)d_out;

    const int n = in_sizes[0] / HIDDEN;   // 50000
    const int E = in_sizes[1] / 2;        // 1600000

    char* ws = (char*)d_ws;
    size_t off = 0;
    auto alloc = [&](size_t bytes) -> void* {
        void* p = (void*)(ws + off);
        off = (off + bytes + 255) & ~((size_t)255);
        return p;
    };
    int*      bcnt2  = (int*)alloc((size_t)NB2 * 4);
    unsigned* pairs2 = (unsigned*)alloc((size_t)NB2 * BCAP2 * 4);
    float*    dis    = (float*)alloc((size_t)n * 4);
    _Float16* h16    = (_Float16*)alloc((size_t)n * NCLS * 2);
    short*    wt_hi  = (short*)alloc((size_t)NCLS * HIDDEN * 2);
    short*    wt_lo  = (short*)alloc((size_t)NCLS * HIDDEN * 2);
    (void)ws_size;

    hipMemsetAsync(bcnt2, 0, (size_t)NB2 * 4, stream);

    wprep_kernel<<<(NCLS * HIDDEN) / 256, 256, 0, stream>>>(W, wt_hi, wt_lo);

    const int nGemm = (n + 127) / 128;                 // 391 tiles of 128 rows
    const int nBucketBlocks = (E + CHUNK - 1) / CHUNK; // 391
    fat_kernel<<<nGemm + nBucketBlocks, 256, 0, stream>>>(
        x, wt_hi, wt_lo, h16, n, ei, pairs2, bcnt2, E, nGemm);

    const int nGroups = (n + 63) / 64;                 // 782
    degree_kernel<<<(nGroups + 3) / 4, 256, 0, stream>>>(pairs2, bcnt2, dis, n);
    agg_kernel<<<nGroups, 256, 0, stream>>>(pairs2, bcnt2, h16, dis, bias, out, n);
}

// Round 12
// 136.608 us; speedup vs baseline: 1.2939x; 1.0219x over previous
//
#include <hip/hip_runtime.h>
#include <hip/hip_bf16.h>
#include <hip/hip_fp16.h>
#include <math.h>

#define HIDDEN 1024
#define NCLS 64
#define NB2 784         // fine groups: group = dst >> 6
#define BCAP2 2560      // per-group capacity (mean 2046)
#define CHUNK 4096      // edges per bucket block
#define KSTEP 32
#define NKS 32          // 1024 / KSTEP
#define BUF 16384       // A[64][32]f32 8KB | Bh[64][32]s16 4KB | Bl 4KB
#define SMEM_BYTES 32800  // max(gemm 2*BUF=32768, bucket 32800)

typedef __attribute__((ext_vector_type(8))) short short8;
typedef __attribute__((ext_vector_type(4))) float f32x4;
typedef __attribute__((ext_vector_type(8))) _Float16 half8;

__device__ __forceinline__ short f2bf(float f) {
    __hip_bfloat16 b = __float2bfloat16(f);
    return __builtin_bit_cast(short, b);
}
__device__ __forceinline__ float bf2f(short s) {
    unsigned u = ((unsigned)(unsigned short)s) << 16;
    return __builtin_bit_cast(float, u);
}

__device__ __forceinline__ void async_copy16(void* lds, const void* g) {
    __builtin_amdgcn_global_load_lds(
        (const __attribute__((address_space(1))) unsigned int*)g,
        (__attribute__((address_space(3))) unsigned int*)lds, 16, 0, 0);
}

// ---------------- W prep: transpose + split bf16 hi/lo, layout [c][k] ----------------
__global__ void wprep_kernel(const float* __restrict__ W,
                             short* __restrict__ wt_hi, short* __restrict__ wt_lo) {
    int idx = blockIdx.x * 256 + threadIdx.x;
    int c = idx >> 10;
    int k = idx & 1023;
    float f = W[(size_t)k * NCLS + c];
    short hb = f2bf(f);
    wt_hi[idx] = hb;
    wt_lo[idx] = f2bf(f - bf2f(hb));
}

// ================= bucket role: per-chunk scatter into fine dst-groups =================
__device__ void bucket_body(char* smem, const int* __restrict__ ei,
                            unsigned* __restrict__ pairs2, int* __restrict__ bcnt2,
                            int E, int bid) {
    int* hist  = (int*)smem;
    int* offs  = hist + 1024;
    int* cur   = offs + 1024;
    int* gbase = cur + 1024;
    unsigned* stage = (unsigned*)(gbase + 1024);
    int* nz = (int*)(stage + CHUNK);
    int* wsum = nz + 1;

    const int tid = threadIdx.x;
    const int base = bid * CHUNK;
    const int cnt_c = min(CHUNK, E - base);

    if (tid == 0) *nz = 0;
    #pragma unroll
    for (int j = 0; j < 4; ++j) { hist[tid + 256 * j] = 0; cur[tid + 256 * j] = 0; }
    __syncthreads();

    int found = 0;
    for (int j = tid; j < 1024; j += 256) {
        int e = base + j;
        if (e < E) found |= (ei[2 * e + 1] != 0);
    }
    if (found) atomicOr(nz, 1);
    __syncthreads();
    const int is64 = (*nz == 0);

    unsigned pr[16];
    #pragma unroll
    for (int j = 0; j < 16; ++j) {
        int e = base + j * 256 + tid;
        unsigned p = 0xFFFFFFFFu;
        if (e < E) {
            int s = is64 ? ei[2 * e] : ei[e];
            int d = is64 ? ei[2 * (E + e)] : ei[E + e];
            p = (unsigned)s | ((unsigned)d << 16);
            atomicAdd(&hist[d >> 6], 1);
        }
        pr[j] = p;
    }
    __syncthreads();

    const int b0 = 4 * tid;
    int h0 = hist[b0], h1 = hist[b0 + 1], h2 = hist[b0 + 2], h3 = hist[b0 + 3];
    int S = h0 + h1 + h2 + h3;
    int incl = S;
    #pragma unroll
    for (int d = 1; d < 64; d <<= 1) {
        int t2 = __shfl_up(incl, d);
        if ((tid & 63) >= d) incl += t2;
    }
    if ((tid & 63) == 63) wsum[tid >> 6] = incl;
    __syncthreads();
    int pre = 0;
    #pragma unroll
    for (int w = 0; w < 4; ++w)
        if (w < (tid >> 6)) pre += wsum[w];
    int ex = pre + incl - S;
    offs[b0] = ex;
    offs[b0 + 1] = ex + h0;
    offs[b0 + 2] = ex + h0 + h1;
    offs[b0 + 3] = ex + h0 + h1 + h2;
    if (h0 > 0) gbase[b0] = atomicAdd(&bcnt2[b0], h0);
    if (h1 > 0) gbase[b0 + 1] = atomicAdd(&bcnt2[b0 + 1], h1);
    if (h2 > 0) gbase[b0 + 2] = atomicAdd(&bcnt2[b0 + 2], h2);
    if (h3 > 0) gbase[b0 + 3] = atomicAdd(&bcnt2[b0 + 3], h3);
    __syncthreads();

    #pragma unroll
    for (int j = 0; j < 16; ++j) {
        unsigned p = pr[j];
        if (p != 0xFFFFFFFFu) {
            int b = (int)(p >> 22);
            int pos = offs[b] + atomicAdd(&cur[b], 1);
            stage[pos] = p;
        }
    }
    __syncthreads();
    for (int i = tid; i < cnt_c; i += 256) {
        unsigned p = stage[i];
        int b = (int)(p >> 22);
        pairs2[(size_t)b * BCAP2 + gbase[b] + (i - offs[b])] = p;
    }
}

// ======== GEMM role: 64-row tile, BK=32, T3-minimum double-buffer pipeline ========
// Per buffer (16KB): A[64r][32f] 128B/row, 16B-slot j holds global chunk j^(r&7);
// Bh/Bl[64c][32s] 64B/col, slot j holds global chunk j^(c&3).
__device__ void gemm_body(char* smem, const float* __restrict__ x,
                          const short* __restrict__ wt_hi, const short* __restrict__ wt_lo,
                          _Float16* __restrict__ h16, int M, int bid) {
    const int tid = threadIdx.x;
    const int wave = tid >> 6;
    const int lane = tid & 63;
    const int l15 = lane & 15, l4 = lane >> 4;
    const int row0 = bid * 64;

    // staging sources (verified R10 geometry): per wave 2 A-loads + Bh + Bl
    const int ar0 = wave * 16 + (lane >> 3);
    const int ar1 = wave * 16 + 8 + (lane >> 3);
    const int ag  = ((lane & 7) ^ ((lane >> 3) & 7)) * 4;
    const int bcol = wave * 16 + (lane >> 2);
    const int bg  = ((lane & 3) ^ ((lane >> 2) & 3)) * 8;

    const float* ap0 = x + (size_t)min(row0 + ar0, M - 1) * HIDDEN + ag;
    const float* ap1 = x + (size_t)min(row0 + ar1, M - 1) * HIDDEN + ag;
    const short* bhp = wt_hi + (size_t)bcol * HIDDEN + bg;
    const short* blp = wt_lo + (size_t)bcol * HIDDEN + bg;

    auto stage_step = [&](char* buf, int k0) {
        async_copy16(buf + wave * 2048, ap0 + k0);
        async_copy16(buf + wave * 2048 + 1024, ap1 + k0);
        async_copy16(buf + 8192 + wave * 1024, bhp + k0);
        async_copy16(buf + 12288 + wave * 1024, blp + k0);
    };

    f32x4 acc[4];
    #pragma unroll
    for (int nf = 0; nf < 4; ++nf) acc[nf] = (f32x4){0.f, 0.f, 0.f, 0.f};

    const int rt = wave * 16 + l15;
    const int abase = rt * 128;
    const int js0 = ((l4 * 2) ^ (rt & 7)) * 16;
    const int js1 = ((l4 * 2 + 1) ^ (rt & 7)) * 16;

    stage_step(smem, 0);
    __syncthreads();
    int cur = 0;
    for (int t = 0; t < NKS; ++t) {
        char* buf = smem + cur * BUF;
        if (t < NKS - 1)
            stage_step(smem + (cur ^ 1) * BUF, (t + 1) * KSTEP);  // issue BEFORE compute

        f32x4 af0 = *reinterpret_cast<const f32x4*>(buf + abase + js0);
        f32x4 af1 = *reinterpret_cast<const f32x4*>(buf + abase + js1);
        short8 ah, al;
        #pragma unroll
        for (int j = 0; j < 4; ++j) {
            short hb = f2bf(af0[j]);
            ah[j] = hb;
            al[j] = f2bf(af0[j] - bf2f(hb));
            short hb2 = f2bf(af1[j]);
            ah[j + 4] = hb2;
            al[j + 4] = f2bf(af1[j] - bf2f(hb2));
        }
        #pragma unroll
        for (int nf = 0; nf < 4; ++nf) {
            int c = l15 + 16 * nf;
            int bo = 8192 + c * 64 + ((l4 ^ (c & 3)) * 16);
            short8 bh = *reinterpret_cast<const short8*>(buf + bo);
            short8 bl = *reinterpret_cast<const short8*>(buf + bo + 4096);
            acc[nf] = __builtin_amdgcn_mfma_f32_16x16x32_bf16(ah, bh, acc[nf], 0, 0, 0);
            acc[nf] = __builtin_amdgcn_mfma_f32_16x16x32_bf16(al, bh, acc[nf], 0, 0, 0);
            acc[nf] = __builtin_amdgcn_mfma_f32_16x16x32_bf16(ah, bl, acc[nf], 0, 0, 0);
        }
        __syncthreads();  // drains residual vmcnt; next-buffer now ready
        cur ^= 1;
    }

    #pragma unroll
    for (int j = 0; j < 4; ++j) {
        int r = row0 + wave * 16 + l4 * 4 + j;
        if (r < M) {
            #pragma unroll
            for (int nf = 0; nf < 4; ++nf) {
                h16[(size_t)r * NCLS + l15 + 16 * nf] = (_Float16)acc[nf][j];
            }
        }
    }
}

// ===== fat: gemm blocks first (LPT, XCD-swizzled tiles), bucket blocks after =====
__global__ __launch_bounds__(256) void fat_kernel(const float* __restrict__ x,
                                                  const short* __restrict__ wt_hi,
                                                  const short* __restrict__ wt_lo,
                                                  _Float16* __restrict__ h16, int M,
                                                  const int* __restrict__ ei,
                                                  unsigned* __restrict__ pairs2,
                                                  int* __restrict__ bcnt2, int E,
                                                  int nGemm) {
    __shared__ __align__(16) char smem[SMEM_BYTES];
    const int bid = blockIdx.x;
    if (bid < nGemm) {
        // bijective XCD-chunk swizzle (m204)
        const int q = nGemm >> 3, r = nGemm & 7;
        int xcd = bid & 7, i = bid >> 3;
        int t = (xcd < r ? xcd * (q + 1) : r * (q + 1) + (xcd - r) * q) + i;
        gemm_body(smem, x, wt_hi, wt_lo, h16, M, t);
    } else {
        bucket_body(smem, ei, pairs2, bcnt2, E, bid - nGemm);
    }
}

// ---------------- per-group degree -> dis ----------------
__global__ __launch_bounds__(256) void degree_kernel(const unsigned* __restrict__ pairs2,
                                                     const int* __restrict__ bcnt2,
                                                     float* __restrict__ dis, int n) {
    __shared__ int hist[256];
    const int tid = threadIdx.x;
    hist[tid] = 0;
    __syncthreads();
    #pragma unroll
    for (int gg = 0; gg < 4; ++gg) {
        int g = blockIdx.x * 4 + gg;
        const int cb = bcnt2[g];
        const unsigned* bp = pairs2 + (size_t)g * BCAP2;
        for (int i = tid; i < cb; i += 256)
            atomicAdd(&hist[gg * 64 + ((bp[i] >> 16) & 63)], 1);
    }
    __syncthreads();
    int node = blockIdx.x * 256 + tid;
    if (node < n) dis[node] = rsqrtf((float)hist[tid] + 1.0f);
}

// ---------------- agg v5: one block per 64-node group ----------------
__global__ __launch_bounds__(256) void agg_kernel(const unsigned* __restrict__ pairs2,
                                                  const int* __restrict__ bcnt2,
                                                  const _Float16* __restrict__ h16,
                                                  const float* __restrict__ dis,
                                                  const float* __restrict__ bias,
                                                  float* __restrict__ out, int n) {
    __shared__ int hist[64];
    __shared__ int offs[64];
    __shared__ int cur[64];
    __shared__ unsigned short ssrc[BCAP2];
    __shared__ float swt[BCAP2];
    const int tid = threadIdx.x;
    const int grp = blockIdx.x;
    const int base_node = grp * 64;
    if (base_node >= n) return;
    if (tid < 64) { hist[tid] = 0; cur[tid] = 0; }
    __syncthreads();
    const int cb = bcnt2[grp];
    const unsigned* bp = pairs2 + (size_t)grp * BCAP2;
    for (int i = tid; i < cb; i += 256)
        atomicAdd(&hist[(bp[i] >> 16) & 63], 1);
    __syncthreads();
    if (tid == 0) {
        int r = 0;
        #pragma unroll
        for (int k = 0; k < 64; ++k) { offs[k] = r; r += hist[k]; }
    }
    __syncthreads();
    for (int i = tid; i < cb; i += 256) {
        unsigned p = bp[i];
        int ln = (p >> 16) & 63;
        int pos = offs[ln] + atomicAdd(&cur[ln], 1);
        int s = (int)(p & 0xFFFFu);
        ssrc[pos] = (unsigned short)s;
        swt[pos] = dis[s];
    }
    __syncthreads();

    const int wave = tid >> 6;
    const int lane = tid & 63;
    const int q = lane & 7;
    const int g = lane >> 3;
    float bv[8];
    #pragma unroll
    for (int c = 0; c < 8; ++c) bv[c] = bias[q * 8 + c];

    for (int t = 0; t < 16; ++t) {
        int ln = wave * 16 + t;
        int node = base_node + ln;
        if (node >= n) continue;
        int len = hist[ln];
        int e0 = offs[ln];
        float di = rsqrtf((float)len + 1.0f);

        half8 hs = *reinterpret_cast<const half8*>(h16 + (size_t)node * NCLS + q * 8);
        float selfw = (g == 0) ? di : 0.f;
        float a[8], a2[8];
        #pragma unroll
        for (int c = 0; c < 8; ++c) { a[c] = (float)hs[c] * selfw; a2[c] = 0.f; }

        for (int i = 0; i < len; i += 16) {
            int i1 = i + g;
            bool v1 = i1 < len;
            int s1 = v1 ? (int)ssrc[e0 + i1] : 0;
            float w1 = v1 ? swt[e0 + i1] : 0.f;
            half8 r1 = *reinterpret_cast<const half8*>(h16 + (size_t)s1 * NCLS + q * 8);
            if (i + 8 < len) {
                int i2 = i + 8 + g;
                bool v2 = i2 < len;
                int s2 = v2 ? (int)ssrc[e0 + i2] : 0;
                float w2 = v2 ? swt[e0 + i2] : 0.f;
                half8 r2 = *reinterpret_cast<const half8*>(h16 + (size_t)s2 * NCLS + q * 8);
                #pragma unroll
                for (int c = 0; c < 8; ++c) a2[c] += w2 * (float)r2[c];
            }
            #pragma unroll
            for (int c = 0; c < 8; ++c) a[c] += w1 * (float)r1[c];
        }
        #pragma unroll
        for (int c = 0; c < 8; ++c) {
            float s = a[c] + a2[c];
            s += __shfl_xor(s, 8);
            s += __shfl_xor(s, 16);
            s += __shfl_xor(s, 32);
            a[c] = s * di + bv[c];
        }
        float m = a[0];
        #pragma unroll
        for (int c = 1; c < 8; ++c) m = fmaxf(m, a[c]);
        #pragma unroll
        for (int d = 1; d < 8; d <<= 1) m = fmaxf(m, __shfl_xor(m, d));
        float ex[8], sum = 0.f;
        #pragma unroll
        for (int c = 0; c < 8; ++c) { ex[c] = __expf(a[c] - m); sum += ex[c]; }
        #pragma unroll
        for (int d = 1; d < 8; d <<= 1) sum += __shfl_xor(sum, d);
        float inv = 1.f / sum;
        if (g == 0) {
            f32x4 o0 = {ex[0] * inv, ex[1] * inv, ex[2] * inv, ex[3] * inv};
            f32x4 o1 = {ex[4] * inv, ex[5] * inv, ex[6] * inv, ex[7] * inv};
            *reinterpret_cast<f32x4*>(out + (size_t)node * NCLS + q * 8) = o0;
            *reinterpret_cast<f32x4*>(out + (size_t)node * NCLS + q * 8 + 4) = o1;
        }
    }
}

// ---------------- launcher ----------------
extern "C" void kernel_launch(void* const* d_in, const int* in_sizes, int n_in,
                              void* d_out, int out_size, void* d_ws, size_t ws_size,
                              hipStream_t stream) {
    const float* x    = (const float*)d_in[0];
    const int*   ei   = (const int*)d_in[1];
    const float* W    = (const float*)d_in[2];
    const float* bias = (const float*)d_in[3];
    float* out = (float*)d_out;

    const int n = in_sizes[0] / HIDDEN;   // 50000
    const int E = in_sizes[1] / 2;        // 1600000

    char* ws = (char*)d_ws;
    size_t off = 0;
    auto alloc = [&](size_t bytes) -> void* {
        void* p = (void*)(ws + off);
        off = (off + bytes + 255) & ~((size_t)255);
        return p;
    };
    int*      bcnt2  = (int*)alloc((size_t)NB2 * 4);
    unsigned* pairs2 = (unsigned*)alloc((size_t)NB2 * BCAP2 * 4);
    float*    dis    = (float*)alloc((size_t)n * 4);
    _Float16* h16    = (_Float16*)alloc((size_t)n * NCLS * 2);
    short*    wt_hi  = (short*)alloc((size_t)NCLS * HIDDEN * 2);
    short*    wt_lo  = (short*)alloc((size_t)NCLS * HIDDEN * 2);
    (void)ws_size;

    hipMemsetAsync(bcnt2, 0, (size_t)NB2 * 4, stream);

    wprep_kernel<<<(NCLS * HIDDEN) / 256, 256, 0, stream>>>(W, wt_hi, wt_lo);

    const int nGemm = (n + 63) / 64;                   // 782 tiles of 64 rows
    const int nBucketBlocks = (E + CHUNK - 1) / CHUNK; // 391
    fat_kernel<<<nGemm + nBucketBlocks, 256, 0, stream>>>(
        x, wt_hi, wt_lo, h16, n, ei, pairs2, bcnt2, E, nGemm);

    const int nGroups = (n + 63) / 64;                 // 782
    degree_kernel<<<(nGroups + 3) / 4, 256, 0, stream>>>(pairs2, bcnt2, dis, n);
    agg_kernel<<<nGroups, 256, 0, stream>>>(pairs2, bcnt2, h16, dis, bias, out, n);
}